// Round 7
// baseline (869.682 us; speedup 1.0000x reference)
//
#include <hip/hip_runtime.h>

// ChebNet on MI355X — Round 7: fp32 state (R6 fp16 failed numerics, reverted).
// Gathers restructured for memory-level parallelism: float4 lanes -> 4-8
// independent nodes per wave, nontemporal CSR stream to protect L2-resident z.

constexpr int N_NODES  = 50000;
constexpr int N_EDGES  = 1600000;
constexpr int N_GRAPHS = 128;

constexpr int NB_H = 256;                 // histogram/place blocks
constexpr int EPB  = N_EDGES / NB_H;      // 6250 edges per block (exact)
constexpr int NW   = (N_NODES + 3) / 4;   // 12500 packed words (4 u8 bins each)

static inline int cdiv(long long a, int b) { return (int)((a + b - 1) / b); }

// ---- CSR build (atomic-free at device scope) ---------------------------

template <int USE_DST>
__global__ __launch_bounds__(256) void hist_kernel(const int* __restrict__ src,
                                                   const int* __restrict__ dst,
                                                   unsigned* __restrict__ H) {
    __shared__ unsigned lds[NW];  // 50 KB: 4 byte-bins per word
    const int b = blockIdx.x, t = threadIdx.x;
    for (int i = t; i < NW; i += 256) lds[i] = 0;
    __syncthreads();
    const int e0 = b * EPB, e1 = e0 + EPB;
    for (int e = e0 + t; e < e1; e += 256) {
        int s = src[e], d = dst[e];
        if (s != d) {
            int key = USE_DST ? d : s;
            atomicAdd(&lds[key >> 2], 1u << (8 * (key & 3)));
        }
    }
    __syncthreads();
    unsigned* Hb = H + (size_t)b * NW;
    for (int i = t; i < NW; i += 256) Hb[i] = lds[i];
}

__global__ void merge_src_kernel(const unsigned* __restrict__ H, float* __restrict__ dinv) {
    int i = blockIdx.x * blockDim.x + threadIdx.x;
    if (i >= NW) return;
    unsigned s0 = 0, s1 = 0, s2 = 0, s3 = 0;
    for (int b = 0; b < NB_H; ++b) {
        unsigned v = H[(size_t)b * NW + i];
        s0 += v & 0xff; s1 += (v >> 8) & 0xff; s2 += (v >> 16) & 0xff; s3 += v >> 24;
    }
    dinv[4 * i + 0] = s0 ? rsqrtf((float)s0) : 0.f;
    dinv[4 * i + 1] = s1 ? rsqrtf((float)s1) : 0.f;
    dinv[4 * i + 2] = s2 ? rsqrtf((float)s2) : 0.f;
    dinv[4 * i + 3] = s3 ? rsqrtf((float)s3) : 0.f;
}

__global__ void merge_dst_kernel(const unsigned* __restrict__ H, unsigned* __restrict__ P,
                                 int* __restrict__ cnt) {
    int i = blockIdx.x * blockDim.x + threadIdx.x;
    if (i >= NW) return;
    unsigned p0 = 0, p1 = 0, p2 = 0, p3 = 0;
    for (int b = 0; b < NB_H; ++b) {
        size_t idx = (size_t)b * NW + i;
        unsigned v = H[idx];
        P[idx] = p0 | (p1 << 8) | (p2 << 16) | (p3 << 24);
        p0 += v & 0xff; p1 += (v >> 8) & 0xff; p2 += (v >> 16) & 0xff; p3 += v >> 24;
    }
    cnt[4 * i + 0] = (int)p0; cnt[4 * i + 1] = (int)p1;
    cnt[4 * i + 2] = (int)p2; cnt[4 * i + 3] = (int)p3;
}

// ---- 3-phase scan ------------------------------------------------------

constexpr int SCAN_B = 256;
constexpr int SCAN_NB = (N_NODES + SCAN_B - 1) / SCAN_B;  // 196

__global__ void scan_block_kernel(const int* __restrict__ cnt, int* __restrict__ row,
                                  int* __restrict__ bsum) {
    __shared__ int buf[SCAN_B];
    int t = threadIdx.x;
    int i = blockIdx.x * SCAN_B + t;
    buf[t] = (i < N_NODES) ? cnt[i] : 0;
    __syncthreads();
    for (int off = 1; off < SCAN_B; off <<= 1) {
        int a = (t >= off) ? buf[t - off] : 0;
        __syncthreads();
        buf[t] += a;
        __syncthreads();
    }
    if (i < N_NODES) row[i + 1] = buf[t];
    if (t == SCAN_B - 1) bsum[blockIdx.x] = buf[t];
    if (i == 0) row[0] = 0;
}

__global__ void scan_sums_kernel(int* __restrict__ bsum) {
    __shared__ int buf[SCAN_NB];
    int t = threadIdx.x;
    if (t < SCAN_NB) buf[t] = bsum[t];
    __syncthreads();
    for (int off = 1; off < SCAN_NB; off <<= 1) {
        int a = (t >= off && t < SCAN_NB) ? buf[t - off] : 0;
        __syncthreads();
        if (t < SCAN_NB) buf[t] += a;
        __syncthreads();
    }
    if (t < SCAN_NB) bsum[t] = buf[t];
}

__global__ void scan_add_kernel(int* __restrict__ row, const int* __restrict__ bsum) {
    int i = blockIdx.x * SCAN_B + threadIdx.x;
    if (blockIdx.x > 0 && i < N_NODES) row[i + 1] += bsum[blockIdx.x - 1];
}

__global__ __launch_bounds__(256) void place_kernel(const int* __restrict__ src,
                                                    const int* __restrict__ dst,
                                                    const float* __restrict__ dinv,
                                                    const int* __restrict__ row,
                                                    const unsigned* __restrict__ P,
                                                    float2* __restrict__ csr) {
    __shared__ unsigned lds[NW];
    const int b = blockIdx.x, t = threadIdx.x;
    for (int i = t; i < NW; i += 256) lds[i] = 0;
    __syncthreads();
    const int e0 = b * EPB, e1 = e0 + EPB;
    const unsigned* Pb = P + (size_t)b * NW;
    for (int e = e0 + t; e < e1; e += 256) {
        int s = src[e], d = dst[e];
        if (s != d) {
            float w = -dinv[s] * dinv[d];
            int sh = 8 * (d & 3);
            unsigned old = atomicAdd(&lds[d >> 2], 1u << sh);
            unsigned cur = (old >> sh) & 0xff;
            unsigned pref = (Pb[d >> 2] >> sh) & 0xff;
            int pos = row[d] + (int)pref + (int)cur;
            csr[pos] = make_float2(w, __int_as_float(s));
        }
    }
}

// ---- L(z) gathers ------------------------------------------------------
// float4-lane version: F/4 lanes per node -> 64/(F/4) independent nodes per
// wave, each with its own csr->row load chain (memory-level parallelism).
// CSR entry read nontemporally (pure stream) so z stays L2-resident.

template <int F>
__global__ __launch_bounds__(256) void gather_v4(const int* __restrict__ row,
                                                 const long long* __restrict__ csr,
                                                 const float4* __restrict__ z4,
                                                 const float4* __restrict__ prev4,
                                                 float4* __restrict__ out4,
                                                 float alpha, float beta) {
    constexpr int LPN = F / 4;        // float4 lanes per node (16 or 8)
    constexpr int NPB = 256 / LPN;    // nodes per block
    int node = blockIdx.x * NPB + threadIdx.x / LPN;
    int l4 = threadIdx.x % LPN;
    if (node >= N_NODES) return;
    int e0 = row[node], e1 = row[node + 1];
    float4 acc = make_float4(0.f, 0.f, 0.f, 0.f);
#pragma unroll 4
    for (int e = e0; e < e1; ++e) {
        long long v = __builtin_nontemporal_load(csr + e);
        float w = __int_as_float((int)(unsigned)v);   // low word = weight
        int s = (int)(v >> 32);                        // high word = src
        float4 zz = z4[(size_t)s * LPN + l4];
        acc.x = fmaf(w, zz.x, acc.x);
        acc.y = fmaf(w, zz.y, acc.y);
        acc.z = fmaf(w, zz.z, acc.z);
        acc.w = fmaf(w, zz.w, acc.w);
    }
    float4 r = make_float4(alpha * acc.x, alpha * acc.y, alpha * acc.z, alpha * acc.w);
    if (beta != 0.f) {
        float4 p = prev4[(size_t)node * LPN + l4];
        r.x = fmaf(beta, p.x, r.x);
        r.y = fmaf(beta, p.y, r.y);
        r.z = fmaf(beta, p.z, r.z);
        r.w = fmaf(beta, p.w, r.w);
    }
    out4[(size_t)node * LPN + l4] = r;
}

// F=4: one thread per node, float4 rows.
__global__ void gather4_kernel(const int* __restrict__ row, const long long* __restrict__ csr,
                               const float* __restrict__ z, const float* __restrict__ prev,
                               float* __restrict__ out, float alpha, float beta) {
    int node = blockIdx.x * blockDim.x + threadIdx.x;
    if (node >= N_NODES) return;
    int e0 = row[node], e1 = row[node + 1];
    const float4* z4 = (const float4*)z;
    float4 a = make_float4(0.f, 0.f, 0.f, 0.f);
#pragma unroll 4
    for (int e = e0; e < e1; ++e) {
        long long v = __builtin_nontemporal_load(csr + e);
        float w = __int_as_float((int)(unsigned)v);
        int s = (int)(v >> 32);
        float4 zz = z4[s];
        a.x = fmaf(w, zz.x, a.x);
        a.y = fmaf(w, zz.y, a.y);
        a.z = fmaf(w, zz.z, a.z);
        a.w = fmaf(w, zz.w, a.w);
    }
    float4 r = make_float4(alpha * a.x, alpha * a.y, alpha * a.z, alpha * a.w);
    if (beta != 0.f) {
        const float4 p = ((const float4*)prev)[node];
        r.x = fmaf(beta, p.x, r.x);
        r.y = fmaf(beta, p.y, r.y);
        r.z = fmaf(beta, p.z, r.z);
        r.w = fmaf(beta, p.w, r.w);
    }
    ((float4*)out)[node] = r;
}

// ---- combine: out[n,o] = relu(b[o] + sum_k T_k[n,:] @ W[k,:,o]) --------

template <int FI>
__global__ __launch_bounds__(256, 4) void combine64_kernel(
        const float* __restrict__ X, const float* __restrict__ T1,
        const float* __restrict__ T2, const float* __restrict__ T3,
        const float* __restrict__ T4, const float* __restrict__ W,
        const float* __restrict__ b, float* __restrict__ out) {
    constexpr int FO = 64;
    constexpr int TS = FI + 4;
    __shared__ float Ts[64 * TS];
    __shared__ float Ws[FI * FO];
    const int t = threadIdx.x;
    const int tn = t & 15;
    const int to = t >> 4;
    const int n_base = blockIdx.x * 64;
    const float* Tk[5] = {X, T1, T2, T3, T4};

    float acc[4][4];
    {
        const float4 bb = *(const float4*)(b + 4 * to);
#pragma unroll
        for (int i = 0; i < 4; ++i) {
            acc[i][0] = bb.x; acc[i][1] = bb.y; acc[i][2] = bb.z; acc[i][3] = bb.w;
        }
    }

#pragma unroll
    for (int k = 0; k < 5; ++k) {
        __syncthreads();
        {
            const float4* s4 = (const float4*)(Tk[k] + (size_t)n_base * FI);
            constexpr int NV = 64 * FI / 4;
#pragma unroll
            for (int idx = t; idx < NV; idx += 256) {
                int r = idx / (FI / 4), c = idx % (FI / 4);
                float4 v = make_float4(0.f, 0.f, 0.f, 0.f);
                if (n_base + r < N_NODES) v = s4[idx];
                *(float4*)(Ts + r * TS + 4 * c) = v;
            }
            const float4* w4 = (const float4*)(W + (size_t)k * FI * FO);
            constexpr int WV = FI * FO / 4;
#pragma unroll
            for (int idx = t; idx < WV; idx += 256) *(float4*)(Ws + 4 * idx) = w4[idx];
        }
        __syncthreads();
#pragma unroll 4
        for (int f0 = 0; f0 < FI; f0 += 4) {
            float tv[4][4];
#pragma unroll
            for (int i = 0; i < 4; ++i) {
                float4 q = *(const float4*)(Ts + (tn + 16 * i) * TS + f0);
                tv[i][0] = q.x; tv[i][1] = q.y; tv[i][2] = q.z; tv[i][3] = q.w;
            }
#pragma unroll
            for (int j = 0; j < 4; ++j) {
                float4 w = *(const float4*)(Ws + (f0 + j) * FO + 4 * to);
#pragma unroll
                for (int i = 0; i < 4; ++i) {
                    acc[i][0] = fmaf(tv[i][j], w.x, acc[i][0]);
                    acc[i][1] = fmaf(tv[i][j], w.y, acc[i][1]);
                    acc[i][2] = fmaf(tv[i][j], w.z, acc[i][2]);
                    acc[i][3] = fmaf(tv[i][j], w.w, acc[i][3]);
                }
            }
        }
    }
    __syncthreads();
#pragma unroll
    for (int i = 0; i < 4; ++i) {
        int n = n_base + tn + 16 * i;
        if (n < N_NODES) {
            float4 r = make_float4(fmaxf(acc[i][0], 0.f), fmaxf(acc[i][1], 0.f),
                                   fmaxf(acc[i][2], 0.f), fmaxf(acc[i][3], 0.f));
            *(float4*)(out + (size_t)n * FO + 4 * to) = r;
        }
    }
}

__global__ void combine432_kernel(const float* __restrict__ X, const float* __restrict__ T1,
                                  const float* __restrict__ T2, const float* __restrict__ T3,
                                  const float* __restrict__ T4, const float* __restrict__ W,
                                  const float* __restrict__ b, float* __restrict__ out) {
    __shared__ float Ws[5 * 4 * 32];
    int t = threadIdx.x;
    for (int i = t; i < 5 * 4 * 32; i += 256) Ws[i] = W[i];
    __syncthreads();
    int node = blockIdx.x * 8 + (t >> 5);
    int o = t & 31;
    if (node >= N_NODES) return;
    const float4* Tk[5] = {(const float4*)X, (const float4*)T1, (const float4*)T2,
                           (const float4*)T3, (const float4*)T4};
    float acc = b[o];
#pragma unroll
    for (int k = 0; k < 5; ++k) {
        float4 q = Tk[k][node];
        const float* w = Ws + k * 128 + o;
        acc = fmaf(q.x, w[0], acc);
        acc = fmaf(q.y, w[32], acc);
        acc = fmaf(q.z, w[64], acc);
        acc = fmaf(q.w, w[96], acc);
    }
    out[(size_t)node * 32 + o] = fmaxf(acc, 0.f);
}

// ---- pooling + MLP -----------------------------------------------------

__global__ void pool_kernel(const float* __restrict__ h, const int* __restrict__ batch,
                            float* __restrict__ pooled, float* __restrict__ cntf) {
    int wid = blockIdx.x * (blockDim.x / 64) + (threadIdx.x >> 6);
    int lane = threadIdx.x & 63;
    int nwaves = gridDim.x * (blockDim.x / 64);
    int per = (N_NODES + nwaves - 1) / nwaves;
    int n0 = wid * per;
    int n1 = min(n0 + per, N_NODES);
    if (n0 >= n1) return;
    int cur = batch[n0];
    float acc = 0.f;
    int c = 0;
    for (int n = n0; n < n1; ++n) {
        int g = batch[n];
        if (g != cur) {
            atomicAdd(&pooled[cur * 64 + lane], acc);
            if (lane == 0) atomicAdd(&cntf[cur], (float)c);
            acc = 0.f; c = 0; cur = g;
        }
        acc += h[(size_t)n * 64 + lane];
        ++c;
    }
    atomicAdd(&pooled[cur * 64 + lane], acc);
    if (lane == 0) atomicAdd(&cntf[cur], (float)c);
}

__global__ void fc_kernel(const float* __restrict__ pooled, const float* __restrict__ cnt,
                          const float* __restrict__ w1, const float* __restrict__ b1,
                          const float* __restrict__ w2, const float* __restrict__ b2,
                          float* __restrict__ out) {
    int g = blockIdx.x;
    int t = threadIdx.x;
    __shared__ float hid[32];
    float c = fmaxf(cnt[g], 1.0f);
    float acc = b1[t];
    for (int f = 0; f < 64; ++f) acc = fmaf(pooled[g * 64 + f] / c, w1[f * 32 + t], acc);
    hid[t] = fmaxf(acc, 0.f);
    __syncthreads();
    if (t == 0) {
        float acc2 = b2[0];
        for (int o = 0; o < 32; ++o) acc2 = fmaf(hid[o], w2[o], acc2);
        out[g] = acc2;
    }
}

// ---- host orchestration ------------------------------------------------

template <int FI, int FO>
static void run_layer(const int* row, const float2* csr, const float* X,
                      float* T1, float* T2, float* T3, float* T4,
                      const float* W, const float* b, float* out, hipStream_t stream) {
    const long long* c8 = (const long long*)csr;
    if constexpr (FI == 4) {
        dim3 g(cdiv(N_NODES, 256)), blk(256);
        hipLaunchKernelGGL(gather4_kernel, g, blk, 0, stream, row, c8, X,  X,  T1, 1.f, 0.f);
        hipLaunchKernelGGL(gather4_kernel, g, blk, 0, stream, row, c8, T1, X,  T2, 2.f, -1.f);
        hipLaunchKernelGGL(gather4_kernel, g, blk, 0, stream, row, c8, T2, T1, T3, 2.f, -1.f);
        hipLaunchKernelGGL(gather4_kernel, g, blk, 0, stream, row, c8, T3, T2, T4, 2.f, -1.f);
    } else {
        constexpr int NPB = 256 / (FI / 4);
        dim3 g(cdiv(N_NODES, NPB)), blk(256);
        const float4* X4 = (const float4*)X;
        float4* T14 = (float4*)T1; float4* T24 = (float4*)T2;
        float4* T34 = (float4*)T3; float4* T44 = (float4*)T4;
        hipLaunchKernelGGL((gather_v4<FI>), g, blk, 0, stream, row, c8, X4,  X4,           T14, 1.f, 0.f);
        hipLaunchKernelGGL((gather_v4<FI>), g, blk, 0, stream, row, c8, (const float4*)T14, X4, T24, 2.f, -1.f);
        hipLaunchKernelGGL((gather_v4<FI>), g, blk, 0, stream, row, c8, (const float4*)T24, (const float4*)T14, T34, 2.f, -1.f);
        hipLaunchKernelGGL((gather_v4<FI>), g, blk, 0, stream, row, c8, (const float4*)T34, (const float4*)T24, T44, 2.f, -1.f);
    }
    if constexpr (FO == 64) {
        hipLaunchKernelGGL((combine64_kernel<FI>), dim3(cdiv(N_NODES, 64)), dim3(256), 0,
                           stream, X, T1, T2, T3, T4, W, b, out);
    } else {
        hipLaunchKernelGGL(combine432_kernel, dim3(cdiv(N_NODES, 8)), dim3(256), 0,
                           stream, X, T1, T2, T3, T4, W, b, out);
    }
}

extern "C" void kernel_launch(void* const* d_in, const int* in_sizes, int n_in,
                              void* d_out, int out_size, void* d_ws, size_t ws_size,
                              hipStream_t stream) {
    const float* x    = (const float*)d_in[0];
    const int*   ei   = (const int*)d_in[1];
    const int*   batch= (const int*)d_in[2];
    const float* W1   = (const float*)d_in[4];
    const float* b1   = (const float*)d_in[5];
    const float* W2   = (const float*)d_in[6];
    const float* b2   = (const float*)d_in[7];
    const float* W3   = (const float*)d_in[8];
    const float* b3   = (const float*)d_in[9];
    const float* fcw1 = (const float*)d_in[10];
    const float* fcb1 = (const float*)d_in[11];
    const float* fcw2 = (const float*)d_in[12];
    const float* fcb2 = (const float*)d_in[13];

    const int* src = ei;
    const int* dst = ei + N_EDGES;

    float* base = (float*)d_ws;
    float*  dinv   = base + 0;                      // 50000
    int*    cnt_i  = (int*)(base + 50000);          // 50000
    int*    row    = (int*)(base + 100000);         // 50004
    int*    bsum   = (int*)(base + 150004);         // 252 -> 150256
    float2* csr    = (float2*)(base + 150256);      // 1.6M float2
    float*  T1     = base + 3350256;
    float*  T2     = base + 6550256;
    float*  T3     = base + 9750256;
    float*  T4     = base + 12950256;
    float*  H1     = T4 + 1600000;                  // layer1 out (F=32), T4 top half
    float*  H2     = base + 16150256;
    float*  pooled = base + 19350256;
    float*  cntf   = base + 19358448;

    unsigned* Hs = (unsigned*)T1;  // build-phase scratch aliases T1..T3
    unsigned* Hd = (unsigned*)T2;
    unsigned* P  = (unsigned*)T3;

    hipLaunchKernelGGL((hist_kernel<0>), dim3(NB_H), dim3(256), 0, stream, src, dst, Hs);
    hipLaunchKernelGGL((hist_kernel<1>), dim3(NB_H), dim3(256), 0, stream, src, dst, Hd);
    hipLaunchKernelGGL(merge_src_kernel, dim3(cdiv(NW, 256)), dim3(256), 0, stream, Hs, dinv);
    hipLaunchKernelGGL(merge_dst_kernel, dim3(cdiv(NW, 256)), dim3(256), 0, stream, Hd, P, cnt_i);
    hipLaunchKernelGGL(scan_block_kernel, dim3(SCAN_NB), dim3(SCAN_B), 0, stream, cnt_i, row, bsum);
    hipLaunchKernelGGL(scan_sums_kernel, dim3(1), dim3(256), 0, stream, bsum);
    hipLaunchKernelGGL(scan_add_kernel, dim3(SCAN_NB), dim3(SCAN_B), 0, stream, row, bsum);
    hipLaunchKernelGGL(place_kernel, dim3(NB_H), dim3(256), 0, stream,
                       src, dst, dinv, row, P, csr);

    run_layer<4, 32>(row, csr, x,  T1, T2, T3, T4, W1, b1, H1, stream);
    run_layer<32, 64>(row, csr, H1, T1, T2, T3, T4, W2, b2, H2, stream);
    run_layer<64, 64>(row, csr, H2, T1, T2, T3, T4, W3, b3, T1, stream);

    hipMemsetAsync(pooled, 0, (8192 + 128) * sizeof(float), stream);
    hipLaunchKernelGGL(pool_kernel, dim3(128), dim3(256), 0, stream, T1, batch, pooled, cntf);
    hipLaunchKernelGGL(fc_kernel, dim3(N_GRAPHS), dim3(32), 0, stream,
                       pooled, cntf, fcw1, fcb1, fcw2, fcb2, (float*)d_out);
}